// Round 1
// baseline (2833.361 us; speedup 1.0000x reference)
//
#include <hip/hip_runtime.h>
#include <hip/hip_bf16.h>

#define D 64

// Scatter: 16 threads per edge, each handles 4 contiguous features via float4.
__global__ void rpi_scatter_kernel(const float* __restrict__ x,
                                   const int* __restrict__ src,
                                   const int* __restrict__ dst,
                                   const float* __restrict__ ew,
                                   float* __restrict__ agg,
                                   int E) {
    int tid = blockIdx.x * blockDim.x + threadIdx.x;
    int e = tid >> 4;              // 16 threads per edge
    if (e >= E) return;
    int c = (tid & 15) << 2;       // feature offset 0..60 step 4
    int s = src[e];
    int d = dst[e];
    float w = ew[e];
    float4 v = *reinterpret_cast<const float4*>(&x[(size_t)s * D + c]);
    float* out = &agg[(size_t)d * D + c];
    atomicAdd(out + 0, w * v.x);
    atomicAdd(out + 1, w * v.y);
    atomicAdd(out + 2, w * v.z);
    atomicAdd(out + 3, w * v.w);
}

// Linear + ReLU: out[n][j] = relu(b[j] + sum_d agg[n][d] * W[j][d])
// One wave per node; lane j owns output column j. W staged in LDS (padded).
__global__ void rpi_linear_relu_kernel(const float* __restrict__ agg,
                                       const float* __restrict__ W,
                                       const float* __restrict__ b,
                                       float* __restrict__ out,
                                       int N) {
    __shared__ float Ws[D][D + 1];
    __shared__ float bs[D];
    int t = threadIdx.x;           // 256 threads = 4 waves
    for (int i = t; i < D * D; i += 256) Ws[i >> 6][i & 63] = W[i];
    if (t < D) bs[t] = b[t];
    __syncthreads();

    int wave = t >> 6;
    int lane = t & 63;
    int nwaves = gridDim.x * 4;
    for (int n = blockIdx.x * 4 + wave; n < N; n += nwaves) {
        const float* arow = &agg[(size_t)n * D];
        float acc = bs[lane];
        #pragma unroll
        for (int d = 0; d < D; ++d) {
            acc = fmaf(arow[d], Ws[lane][d], acc);
        }
        out[(size_t)n * D + lane] = fmaxf(acc, 0.0f);
    }
}

extern "C" void kernel_launch(void* const* d_in, const int* in_sizes, int n_in,
                              void* d_out, int out_size, void* d_ws, size_t ws_size,
                              hipStream_t stream) {
    const float* x0  = (const float*)d_in[0];   // [N, 64]
    const int*   ei  = (const int*)d_in[1];     // [2, E]
    const float* ew  = (const float*)d_in[2];   // [E]
    const float* W   = (const float*)d_in[3];   // [64, 64]
    const float* b   = (const float*)d_in[4];   // [64]
    float* out = (float*)d_out;                 // [N, 64]
    float* agg = (float*)d_ws;                  // [N, 64] scratch

    int N = in_sizes[0] / D;
    int E = in_sizes[2];
    const int* src = ei;
    const int* dst = ei + E;

    const float* xcur = x0;
    int scatter_threads = E * 16;
    int scatter_blocks = (scatter_threads + 255) / 256;

    for (int it = 0; it < 3; ++it) {
        hipMemsetAsync(agg, 0, (size_t)N * D * sizeof(float), stream);
        rpi_scatter_kernel<<<scatter_blocks, 256, 0, stream>>>(xcur, src, dst, ew, agg, E);
        rpi_linear_relu_kernel<<<2048, 256, 0, stream>>>(agg, W, b, out, N);
        xcur = out;
    }
}

// Round 2
// 533.673 us; speedup vs baseline: 5.3092x; 5.3092x over previous
//
#include <hip/hip_runtime.h>
#include <hip/hip_bf16.h>

#define D 64

// ---------- CSR build ----------
__global__ void hist_kernel(const int* __restrict__ dst, int* __restrict__ counts, int E) {
    int e = blockIdx.x * blockDim.x + threadIdx.x;
    if (e < E) atomicAdd(&counts[dst[e]], 1);
}

// Allocate a contiguous region per node (order nondeterministic, but regions
// are disjoint and complete -> output within fp-threshold like any atomic sum).
__global__ void alloc_kernel(const int* __restrict__ counts, int* __restrict__ start,
                             int* __restrict__ cursor, int* __restrict__ total, int N) {
    int n = blockIdx.x * blockDim.x + threadIdx.x;
    if (n < N) {
        int c = counts[n];
        int s = atomicAdd(total, c);
        start[n]  = s;
        cursor[n] = s;
    }
}

__global__ void fill_kernel(const int* __restrict__ src, const int* __restrict__ dst,
                            const float* __restrict__ ew, int* __restrict__ cursor,
                            float2* __restrict__ perm, int E) {
    int e = blockIdx.x * blockDim.x + threadIdx.x;
    if (e < E) {
        int p = atomicAdd(&cursor[dst[e]], 1);
        perm[p] = make_float2(__int_as_float(src[e]), ew[e]);
    }
}

// ---------- fused aggregate + linear + relu ----------
// One wave per node, lane = feature. Gather incoming edges (coalesced 256B row
// reads), then fused 64x64 linear via v_readlane broadcast + LDS-staged W.
__global__ void gather_linear_kernel(const float* __restrict__ x,
                                     const float2* __restrict__ perm,
                                     const int* __restrict__ start,
                                     const int* __restrict__ counts,
                                     const float* __restrict__ W,
                                     const float* __restrict__ bias,
                                     float* __restrict__ out, int N) {
    __shared__ float Ws[D][D + 1];
    __shared__ float bs[D];
    int t = threadIdx.x;                       // 256 threads = 4 waves
    for (int i = t; i < D * D; i += 256) Ws[i >> 6][i & 63] = W[i];
    if (t < D) bs[t] = bias[t];
    __syncthreads();

    int wave = t >> 6;
    int lane = t & 63;
    int nwaves = gridDim.x * 4;
    for (int n = blockIdx.x * 4 + wave; n < N; n += nwaves) {
        int st  = start[n];
        int cnt = counts[n];
        float acc = 0.0f;
        for (int k = 0; k < cnt; ++k) {
            float2 m = perm[st + k];                       // wave-uniform 8B load
            int s = __float_as_int(m.x);
            acc = fmaf(m.y, x[(size_t)s * D + lane], acc); // coalesced row read
        }
        // out[n][lane] = relu(b[lane] + sum_d acc_d * W[lane][d])
        float o = bs[lane];
        #pragma unroll
        for (int d = 0; d < D; ++d) {
            float a = __int_as_float(__builtin_amdgcn_readlane(__float_as_int(acc), d));
            o = fmaf(a, Ws[lane][d], o);                   // Ws stride 65: conflict-free
        }
        out[(size_t)n * D + lane] = fmaxf(o, 0.0f);
    }
}

// ---------- fallback (round-1 path) if ws too small ----------
__global__ void rpi_scatter_kernel(const float* __restrict__ x,
                                   const int* __restrict__ src,
                                   const int* __restrict__ dst,
                                   const float* __restrict__ ew,
                                   float* __restrict__ agg, int E) {
    int tid = blockIdx.x * blockDim.x + threadIdx.x;
    int e = tid >> 4;
    if (e >= E) return;
    int c = (tid & 15) << 2;
    int s = src[e], d = dst[e];
    float w = ew[e];
    float4 v = *reinterpret_cast<const float4*>(&x[(size_t)s * D + c]);
    float* o = &agg[(size_t)d * D + c];
    atomicAdd(o + 0, w * v.x);
    atomicAdd(o + 1, w * v.y);
    atomicAdd(o + 2, w * v.z);
    atomicAdd(o + 3, w * v.w);
}

__global__ void rpi_linear_relu_kernel(const float* __restrict__ agg,
                                       const float* __restrict__ W,
                                       const float* __restrict__ b,
                                       float* __restrict__ out, int N) {
    __shared__ float Ws[D][D + 1];
    __shared__ float bs[D];
    int t = threadIdx.x;
    for (int i = t; i < D * D; i += 256) Ws[i >> 6][i & 63] = W[i];
    if (t < D) bs[t] = b[t];
    __syncthreads();
    int wave = t >> 6, lane = t & 63;
    int nwaves = gridDim.x * 4;
    for (int n = blockIdx.x * 4 + wave; n < N; n += nwaves) {
        const float* arow = &agg[(size_t)n * D];
        float acc = bs[lane];
        #pragma unroll
        for (int d = 0; d < D; ++d) acc = fmaf(arow[d], Ws[lane][d], acc);
        out[(size_t)n * D + lane] = fmaxf(acc, 0.0f);
    }
}

extern "C" void kernel_launch(void* const* d_in, const int* in_sizes, int n_in,
                              void* d_out, int out_size, void* d_ws, size_t ws_size,
                              hipStream_t stream) {
    const float* x0 = (const float*)d_in[0];   // [N, 64]
    const int*   ei = (const int*)d_in[1];     // [2, E]
    const float* ew = (const float*)d_in[2];   // [E]
    const float* W  = (const float*)d_in[3];   // [64, 64]
    const float* b  = (const float*)d_in[4];   // [64]
    float* out = (float*)d_out;                // [N, 64]

    int N = in_sizes[0] / D;
    int E = in_sizes[2];
    const int* src = ei;
    const int* dst = ei + E;

    size_t xbytes   = (size_t)N * D * sizeof(float);
    size_t intBytes = ((size_t)3 * N + 2) * sizeof(int);   // counts,start,cursor,total (+pad to 8B)
    size_t need     = xbytes + intBytes + (size_t)E * sizeof(float2);

    if (ws_size >= need) {
        float*  xbuf   = (float*)d_ws;
        int*    counts = (int*)((char*)d_ws + xbytes);
        int*    start  = counts + N;
        int*    cursor = start + N;
        int*    total  = cursor + N;
        float2* perm   = (float2*)((char*)d_ws + xbytes + intBytes);

        hipMemsetAsync(counts, 0, intBytes, stream);
        int eb = (E + 255) / 256;
        int nb = (N + 255) / 256;
        hist_kernel <<<eb, 256, 0, stream>>>(dst, counts, E);
        alloc_kernel<<<nb, 256, 0, stream>>>(counts, start, cursor, total, N);
        fill_kernel <<<eb, 256, 0, stream>>>(src, dst, ew, cursor, perm, E);

        gather_linear_kernel<<<2048, 256, 0, stream>>>(x0,  perm, start, counts, W, b, out,  N);
        gather_linear_kernel<<<2048, 256, 0, stream>>>(out, perm, start, counts, W, b, xbuf, N);
        gather_linear_kernel<<<2048, 256, 0, stream>>>(xbuf, perm, start, counts, W, b, out, N);
    } else {
        // fallback: round-1 atomic path (needs only xbytes of ws)
        float* agg = (float*)d_ws;
        const float* xcur = x0;
        int sb = (E * 16 + 255) / 256;
        for (int it = 0; it < 3; ++it) {
            hipMemsetAsync(agg, 0, xbytes, stream);
            rpi_scatter_kernel<<<sb, 256, 0, stream>>>(xcur, src, dst, ew, agg, E);
            rpi_linear_relu_kernel<<<2048, 256, 0, stream>>>(agg, W, b, out, N);
            xcur = out;
        }
    }
}

// Round 4
// 383.235 us; speedup vs baseline: 7.3933x; 1.3925x over previous
//
#include <hip/hip_runtime.h>
#include <hip/hip_bf16.h>

#define D 64

// ---------- CSR build ----------
__global__ void hist_kernel(const int* __restrict__ dst, int* __restrict__ counts, int E) {
    int e = blockIdx.x * blockDim.x + threadIdx.x;
    if (e < E) atomicAdd(&counts[dst[e]], 1);
}

// Region placement via atomic is nondeterministic, but placement doesn't affect
// the per-node sum; only within-segment ORDER does (fixed by sort_kernel below).
__global__ void alloc_kernel(const int* __restrict__ counts, int* __restrict__ start,
                             int* __restrict__ cursor, int* __restrict__ total, int N) {
    int n = blockIdx.x * blockDim.x + threadIdx.x;
    if (n < N) {
        int c = counts[n];
        int s = atomicAdd(total, c);
        start[n]  = s;
        cursor[n] = s;
    }
}

__global__ void fill_kernel(const int* __restrict__ src, const int* __restrict__ dst,
                            const float* __restrict__ ew, int* __restrict__ cursor,
                            float2* __restrict__ perm, int E) {
    int e = blockIdx.x * blockDim.x + threadIdx.x;
    if (e < E) {
        int p = atomicAdd(&cursor[dst[e]], 1);
        perm[p] = make_float2(__int_as_float(src[e]), ew[e]);
    }
}

// Canonicalize within-node order: ascending uint64 view of (src,w) pairs.
// Equal keys are identical values (interchangeable), so the sorted sequence —
// and hence the fp summation order — is a pure function of the inputs.
// This kills the replay-to-replay nondeterminism that flipped ReLU gates.
__global__ void sort_kernel(unsigned long long* __restrict__ perm64,
                            const int* __restrict__ start,
                            const int* __restrict__ counts, int N) {
    int n = blockIdx.x * blockDim.x + threadIdx.x;
    if (n >= N) return;
    int st = start[n], cnt = counts[n];
    for (int i = 1; i < cnt; ++i) {
        unsigned long long key = perm64[st + i];
        int j = i - 1;
        while (j >= 0 && perm64[st + j] > key) {
            perm64[st + j + 1] = perm64[st + j];
            --j;
        }
        perm64[st + j + 1] = key;
    }
}

// ---------- fused aggregate + linear + relu ----------
// One wave per node. 4 lane-groups of 16 stream 4 edges concurrently
// (16 lanes x float4 = 256B row each) -> 4 gathers in flight per wave,
// cnt/4 loop iterations. Cross-group shfl_xor reduce, then fused 64x64
// linear via readlane broadcast + LDS-staged W (stride 65, conflict-free).
__global__ void gather_linear_kernel(const float* __restrict__ x,
                                     const float2* __restrict__ perm,
                                     const int* __restrict__ start,
                                     const int* __restrict__ counts,
                                     const float* __restrict__ W,
                                     const float* __restrict__ bias,
                                     float* __restrict__ out, int N) {
    __shared__ float Ws[D][D + 1];
    __shared__ float bs[D];
    int t = threadIdx.x;                       // 256 threads = 4 waves
    for (int i = t; i < D * D; i += 256) Ws[i >> 6][i & 63] = W[i];
    if (t < D) bs[t] = bias[t];
    __syncthreads();

    int wave = t >> 6;
    int lane = t & 63;
    int g = lane >> 4;            // edge sub-stream 0..3
    int c = (lane & 15) << 2;     // feature quad base 0..60
    int nwaves = gridDim.x * 4;
    for (int n = blockIdx.x * 4 + wave; n < N; n += nwaves) {
        int st  = start[n];
        int cnt = counts[n];
        float ax = 0.f, ay = 0.f, az = 0.f, aw = 0.f;
        for (int k = g; k < cnt; k += 4) {
            float2 m = perm[st + k];                     // per-group 8B (bcast in group)
            int s = __float_as_int(m.x);
            float w = m.y;
            float4 v = *reinterpret_cast<const float4*>(&x[(size_t)s * D + c]);
            ax = fmaf(w, v.x, ax);
            ay = fmaf(w, v.y, ay);
            az = fmaf(w, v.z, az);
            aw = fmaf(w, v.w, aw);
        }
        // reduce across the 4 groups (lane bits 4,5)
        #pragma unroll
        for (int mask = 16; mask <= 32; mask <<= 1) {
            ax += __shfl_xor(ax, mask);
            ay += __shfl_xor(ay, mask);
            az += __shfl_xor(az, mask);
            aw += __shfl_xor(aw, mask);
        }
        // out[n][lane] = relu(b[lane] + sum_d agg[d] * W[lane][d])
        float o = bs[lane];
        #pragma unroll
        for (int d = 0; d < D; ++d) {
            float comp = ((d & 3) == 0) ? ax : ((d & 3) == 1) ? ay : ((d & 3) == 2) ? az : aw;
            float a = __int_as_float(__builtin_amdgcn_readlane(__float_as_int(comp), d >> 2));
            o = fmaf(a, Ws[lane][d], o);
        }
        out[(size_t)n * D + lane] = fmaxf(o, 0.0f);
    }
}

// ---------- fallback (atomic path) if ws too small ----------
__global__ void rpi_scatter_kernel(const float* __restrict__ x,
                                   const int* __restrict__ src,
                                   const int* __restrict__ dst,
                                   const float* __restrict__ ew,
                                   float* __restrict__ agg, int E) {
    int tid = blockIdx.x * blockDim.x + threadIdx.x;
    int e = tid >> 4;
    if (e >= E) return;
    int c = (tid & 15) << 2;
    int s = src[e], d = dst[e];
    float w = ew[e];
    float4 v = *reinterpret_cast<const float4*>(&x[(size_t)s * D + c]);
    float* o = &agg[(size_t)d * D + c];
    atomicAdd(o + 0, w * v.x);
    atomicAdd(o + 1, w * v.y);
    atomicAdd(o + 2, w * v.z);
    atomicAdd(o + 3, w * v.w);
}

__global__ void rpi_linear_relu_kernel(const float* __restrict__ agg,
                                       const float* __restrict__ W,
                                       const float* __restrict__ b,
                                       float* __restrict__ out, int N) {
    __shared__ float Ws[D][D + 1];
    __shared__ float bs[D];
    int t = threadIdx.x;
    for (int i = t; i < D * D; i += 256) Ws[i >> 6][i & 63] = W[i];
    if (t < D) bs[t] = b[t];
    __syncthreads();
    int wave = t >> 6, lane = t & 63;
    int nwaves = gridDim.x * 4;
    for (int n = blockIdx.x * 4 + wave; n < N; n += nwaves) {
        const float* arow = &agg[(size_t)n * D];
        float acc = bs[lane];
        #pragma unroll
        for (int d = 0; d < D; ++d) acc = fmaf(arow[d], Ws[lane][d], acc);
        out[(size_t)n * D + lane] = fmaxf(acc, 0.0f);
    }
}

extern "C" void kernel_launch(void* const* d_in, const int* in_sizes, int n_in,
                              void* d_out, int out_size, void* d_ws, size_t ws_size,
                              hipStream_t stream) {
    const float* x0 = (const float*)d_in[0];   // [N, 64]
    const int*   ei = (const int*)d_in[1];     // [2, E]
    const float* ew = (const float*)d_in[2];   // [E]
    const float* W  = (const float*)d_in[3];   // [64, 64]
    const float* b  = (const float*)d_in[4];   // [64]
    float* out = (float*)d_out;                // [N, 64]

    int N = in_sizes[0] / D;
    int E = in_sizes[2];
    const int* src = ei;
    const int* dst = ei + E;

    size_t xbytes   = (size_t)N * D * sizeof(float);
    size_t intBytes = ((size_t)3 * N + 2) * sizeof(int);   // counts,start,cursor,total
    size_t need     = xbytes + intBytes + (size_t)E * sizeof(float2);

    if (ws_size >= need) {
        float*  xbuf   = (float*)d_ws;
        int*    counts = (int*)((char*)d_ws + xbytes);
        int*    start  = counts + N;
        int*    cursor = start + N;
        int*    total  = cursor + N;
        float2* perm   = (float2*)((char*)d_ws + xbytes + intBytes);

        hipMemsetAsync(counts, 0, intBytes, stream);
        int eb = (E + 255) / 256;
        int nb = (N + 255) / 256;
        hist_kernel <<<eb, 256, 0, stream>>>(dst, counts, E);
        alloc_kernel<<<nb, 256, 0, stream>>>(counts, start, cursor, total, N);
        fill_kernel <<<eb, 256, 0, stream>>>(src, dst, ew, cursor, perm, E);
        sort_kernel <<<nb, 256, 0, stream>>>((unsigned long long*)perm, start, counts, N);

        gather_linear_kernel<<<4096, 256, 0, stream>>>(x0,   perm, start, counts, W, b, out,  N);
        gather_linear_kernel<<<4096, 256, 0, stream>>>(out,  perm, start, counts, W, b, xbuf, N);
        gather_linear_kernel<<<4096, 256, 0, stream>>>(xbuf, perm, start, counts, W, b, out,  N);
    } else {
        float* agg = (float*)d_ws;
        const float* xcur = x0;
        int sb = (E * 16 + 255) / 256;
        for (int it = 0; it < 3; ++it) {
            hipMemsetAsync(agg, 0, xbytes, stream);
            rpi_scatter_kernel<<<sb, 256, 0, stream>>>(xcur, src, dst, ew, agg, E);
            rpi_linear_relu_kernel<<<2048, 256, 0, stream>>>(agg, W, b, out, N);
            xcur = out;
        }
    }
}

// Round 5
// 372.350 us; speedup vs baseline: 7.6094x; 1.0292x over previous
//
#include <hip/hip_runtime.h>
#include <hip/hip_bf16.h>

#define D 64
#define FP_SCALE 1048576.0f          // 2^20
#define FP_INV   (1.0f / 1048576.0f)

// ---------- CSR build ----------
__global__ void hist_kernel(const int* __restrict__ dst, int* __restrict__ counts, int E) {
    int e = blockIdx.x * blockDim.x + threadIdx.x;
    if (e < E) atomicAdd(&counts[dst[e]], 1);
}

// Region placement via atomic is nondeterministic, but the gather's integer
// accumulation is order-independent, so placement/order never affect the sum.
// counts[] is recycled as the fill cursor.
__global__ void alloc_kernel(int* __restrict__ counts_cursor, int2* __restrict__ seg,
                             int* __restrict__ total, int N) {
    int n = blockIdx.x * blockDim.x + threadIdx.x;
    if (n < N) {
        int c = counts_cursor[n];
        int s = atomicAdd(total, c);
        seg[n] = make_int2(s, c);
        counts_cursor[n] = s;        // becomes cursor for fill
    }
}

__global__ void fill_kernel(const int* __restrict__ src, const int* __restrict__ dst,
                            const float* __restrict__ ew, int* __restrict__ cursor,
                            float2* __restrict__ perm, int E) {
    int e = blockIdx.x * blockDim.x + threadIdx.x;
    if (e < E) {
        int p = atomicAdd(&cursor[dst[e]], 1);
        perm[p] = make_float2(__int_as_float(src[e]), ew[e]);
    }
}

// ---------- fused aggregate + linear + relu ----------
// One wave per node. 4 lane-groups of 16 stream edges (16 lanes x float4 =
// 256B row each), unrolled x2 -> 8 row gathers in flight per wave.
// Messages accumulate in int32 fixed point (scale 2^20): integer addition is
// associative, so the node sum is independent of CSR arrival order ->
// deterministic across graph replays with no sort. Cross-group reduce stays
// integer; convert once, then fused 64x64 linear via readlane + LDS W.
__global__ void gather_linear_kernel(const float* __restrict__ x,
                                     const float2* __restrict__ perm,
                                     const int2* __restrict__ seg,
                                     const float* __restrict__ W,
                                     const float* __restrict__ bias,
                                     float* __restrict__ out, int N) {
    __shared__ float Ws[D][D + 1];
    __shared__ float bs[D];
    int t = threadIdx.x;                       // 256 threads = 4 waves
    for (int i = t; i < D * D; i += 256) Ws[i >> 6][i & 63] = W[i];
    if (t < D) bs[t] = bias[t];
    __syncthreads();

    int wave = t >> 6;
    int lane = t & 63;
    int g = lane >> 4;            // edge sub-stream 0..3
    int c = (lane & 15) << 2;     // feature quad base 0..60
    int nwaves = gridDim.x * 4;
    for (int n = blockIdx.x * 4 + wave; n < N; n += nwaves) {
        int2 sc = seg[n];
        int st = sc.x, cnt = sc.y;
        int ix = 0, iy = 0, iz = 0, iw = 0;
        int k = g;
        for (; k + 4 < cnt; k += 8) {          // unroll x2: both loads in flight
            float2 m0 = perm[st + k];
            float2 m1 = perm[st + k + 4];
            int s0 = __float_as_int(m0.x);
            int s1 = __float_as_int(m1.x);
            float w0 = m0.y * FP_SCALE;
            float w1 = m1.y * FP_SCALE;
            float4 v0 = *reinterpret_cast<const float4*>(&x[(size_t)s0 * D + c]);
            float4 v1 = *reinterpret_cast<const float4*>(&x[(size_t)s1 * D + c]);
            ix += (int)(w0 * v0.x) + (int)(w1 * v1.x);
            iy += (int)(w0 * v0.y) + (int)(w1 * v1.y);
            iz += (int)(w0 * v0.z) + (int)(w1 * v1.z);
            iw += (int)(w0 * v0.w) + (int)(w1 * v1.w);
        }
        if (k < cnt) {                          // tail
            float2 m0 = perm[st + k];
            int s0 = __float_as_int(m0.x);
            float w0 = m0.y * FP_SCALE;
            float4 v0 = *reinterpret_cast<const float4*>(&x[(size_t)s0 * D + c]);
            ix += (int)(w0 * v0.x);
            iy += (int)(w0 * v0.y);
            iz += (int)(w0 * v0.z);
            iw += (int)(w0 * v0.w);
        }
        // integer reduce across the 4 groups (lane bits 4,5) -- order-free
        #pragma unroll
        for (int mask = 16; mask <= 32; mask <<= 1) {
            ix += __shfl_xor(ix, mask);
            iy += __shfl_xor(iy, mask);
            iz += __shfl_xor(iz, mask);
            iw += __shfl_xor(iw, mask);
        }
        float ax = (float)ix * FP_INV;
        float ay = (float)iy * FP_INV;
        float az = (float)iz * FP_INV;
        float aw = (float)iw * FP_INV;
        // out[n][lane] = relu(b[lane] + sum_d agg[d] * W[lane][d])
        float o = bs[lane];
        #pragma unroll
        for (int d = 0; d < D; ++d) {
            float comp = ((d & 3) == 0) ? ax : ((d & 3) == 1) ? ay : ((d & 3) == 2) ? az : aw;
            float a = __int_as_float(__builtin_amdgcn_readlane(__float_as_int(comp), d >> 2));
            o = fmaf(a, Ws[lane][d], o);
        }
        out[(size_t)n * D + lane] = fmaxf(o, 0.0f);
    }
}

// ---------- fallback (int-atomic path, deterministic) if ws too small ----------
__global__ void rpi_scatter_kernel(const float* __restrict__ x,
                                   const int* __restrict__ src,
                                   const int* __restrict__ dst,
                                   const float* __restrict__ ew,
                                   int* __restrict__ agg, int E) {
    int tid = blockIdx.x * blockDim.x + threadIdx.x;
    int e = tid >> 4;
    if (e >= E) return;
    int c = (tid & 15) << 2;
    int s = src[e], d = dst[e];
    float w = ew[e] * FP_SCALE;
    float4 v = *reinterpret_cast<const float4*>(&x[(size_t)s * D + c]);
    int* o = &agg[(size_t)d * D + c];
    atomicAdd(o + 0, (int)(w * v.x));
    atomicAdd(o + 1, (int)(w * v.y));
    atomicAdd(o + 2, (int)(w * v.z));
    atomicAdd(o + 3, (int)(w * v.w));
}

__global__ void rpi_linear_relu_kernel(const int* __restrict__ agg,
                                       const float* __restrict__ W,
                                       const float* __restrict__ b,
                                       float* __restrict__ out, int N) {
    __shared__ float Ws[D][D + 1];
    __shared__ float bs[D];
    int t = threadIdx.x;
    for (int i = t; i < D * D; i += 256) Ws[i >> 6][i & 63] = W[i];
    if (t < D) bs[t] = b[t];
    __syncthreads();
    int wave = t >> 6, lane = t & 63;
    int nwaves = gridDim.x * 4;
    for (int n = blockIdx.x * 4 + wave; n < N; n += nwaves) {
        const int* arow = &agg[(size_t)n * D];
        float acc = bs[lane];
        #pragma unroll
        for (int d = 0; d < D; ++d) acc = fmaf((float)arow[d] * FP_INV, Ws[lane][d], acc);
        out[(size_t)n * D + lane] = fmaxf(acc, 0.0f);
    }
}

extern "C" void kernel_launch(void* const* d_in, const int* in_sizes, int n_in,
                              void* d_out, int out_size, void* d_ws, size_t ws_size,
                              hipStream_t stream) {
    const float* x0 = (const float*)d_in[0];   // [N, 64]
    const int*   ei = (const int*)d_in[1];     // [2, E]
    const float* ew = (const float*)d_in[2];   // [E]
    const float* W  = (const float*)d_in[3];   // [64, 64]
    const float* b  = (const float*)d_in[4];   // [64]
    float* out = (float*)d_out;                // [N, 64]

    int N = in_sizes[0] / D;
    int E = in_sizes[2];
    const int* src = ei;
    const int* dst = ei + E;

    size_t xbytes   = (size_t)N * D * sizeof(float);
    size_t intBytes = ((size_t)3 * N + 2) * sizeof(int);   // seg(2N) + cursor(N) + total(+pad)
    size_t need     = xbytes + intBytes + (size_t)E * sizeof(float2);

    if (ws_size >= need) {
        float*  xbuf   = (float*)d_ws;
        int2*   seg    = (int2*)((char*)d_ws + xbytes);
        int*    cursor = (int*)(seg + N);
        float2* perm   = (float2*)((char*)d_ws + xbytes + intBytes);
        int*    total  = cursor + N;

        hipMemsetAsync(cursor, 0, (size_t)(N + 2) * sizeof(int), stream);  // cursor + total
        int eb = (E + 255) / 256;
        int nb = (N + 255) / 256;
        hist_kernel <<<eb, 256, 0, stream>>>(dst, cursor, E);
        alloc_kernel<<<nb, 256, 0, stream>>>(cursor, seg, total, N);
        fill_kernel <<<eb, 256, 0, stream>>>(src, dst, ew, cursor, perm, E);

        gather_linear_kernel<<<4096, 256, 0, stream>>>(x0,   perm, seg, W, b, out,  N);
        gather_linear_kernel<<<4096, 256, 0, stream>>>(out,  perm, seg, W, b, xbuf, N);
        gather_linear_kernel<<<4096, 256, 0, stream>>>(xbuf, perm, seg, W, b, out,  N);
    } else {
        int* agg = (int*)d_ws;
        const float* xcur = x0;
        int sb = (E * 16 + 255) / 256;
        for (int it = 0; it < 3; ++it) {
            hipMemsetAsync(agg, 0, xbytes, stream);
            rpi_scatter_kernel<<<sb, 256, 0, stream>>>(xcur, src, dst, ew, agg, E);
            rpi_linear_relu_kernel<<<2048, 256, 0, stream>>>(agg, W, b, out, N);
            xcur = out;
        }
    }
}

// Round 6
// 332.308 us; speedup vs baseline: 8.5263x; 1.1205x over previous
//
#include <hip/hip_runtime.h>
#include <hip/hip_bf16.h>

#define D 64
#define FP_SCALE 262144.0f          // 2^18 (order-free int accumulation)
#define FP_INV   (1.0f / 262144.0f)

__device__ __forceinline__ unsigned short f2bf(float f) {   // rtne f32->bf16
    unsigned int u = __float_as_uint(f);
    u += 0x7fffu + ((u >> 16) & 1u);
    return (unsigned short)(u >> 16);
}

// ---------- CSR build ----------
__global__ void hist_kernel(const int* __restrict__ dst, int* __restrict__ counts, int E) {
    int e = blockIdx.x * blockDim.x + threadIdx.x;
    if (e < E) atomicAdd(&counts[dst[e]], 1);
}

// Wave-scan allocator: inclusive __shfl_up scan + ONE atomic per wave
// (was 100K serialized atomics to a single address).
__global__ void alloc_kernel(int* __restrict__ counts_cursor, int2* __restrict__ seg,
                             int* __restrict__ total, int N) {
    int n = blockIdx.x * blockDim.x + threadIdx.x;
    int lane = threadIdx.x & 63;
    int c = (n < N) ? counts_cursor[n] : 0;
    int incl = c;
    #pragma unroll
    for (int off = 1; off < 64; off <<= 1) {
        int t = __shfl_up(incl, off);
        if (lane >= off) incl += t;
    }
    int wsum = __shfl(incl, 63);
    int base = 0;
    if (lane == 63) base = atomicAdd(total, wsum);
    base = __shfl(base, 63);
    if (n < N) {
        int st = base + incl - c;
        seg[n] = make_int2(st, c);
        counts_cursor[n] = st;      // becomes cursor for fill
    }
}

// Placement within a segment is atomic-order nondeterministic, but the
// gather's integer accumulation is order-free, so the sum is input-pure.
// w is pre-scaled by 2^18 here (exact: exponent shift).
__global__ void fill_kernel(const int* __restrict__ src, const int* __restrict__ dst,
                            const float* __restrict__ ew, int* __restrict__ cursor,
                            float2* __restrict__ perm, int E) {
    int e = blockIdx.x * blockDim.x + threadIdx.x;
    if (e < E) {
        int p = atomicAdd(&cursor[dst[e]], 1);
        perm[p] = make_float2(__int_as_float(src[e]), ew[e] * FP_SCALE);
    }
}

// f32 -> bf16 convert (for iteration 0 input)
__global__ void cvt_kernel(const float* __restrict__ in, unsigned short* __restrict__ out, int n4) {
    int i = blockIdx.x * blockDim.x + threadIdx.x;
    if (i >= n4) return;
    float4 v = reinterpret_cast<const float4*>(in)[i];
    ushort4 o;
    o.x = f2bf(v.x); o.y = f2bf(v.y); o.z = f2bf(v.z); o.w = f2bf(v.w);
    reinterpret_cast<ushort4*>(out)[i] = o;
}

// ---------- fused aggregate + linear + relu ----------
// One wave per node. 4 lane-groups of 16 stream edges; rows are bf16
// (16 lanes x 8B = 128B row), unrolled x2 -> 8 row gathers in flight.
// int32 fixed-point accumulation (scale 2^18) keeps the node sum independent
// of CSR arrival order -> bit-deterministic across graph replays, no sort.
template<bool OUT_BF>
__global__ void gather_linear_kernel(const unsigned short* __restrict__ xb,
                                     const float2* __restrict__ perm,
                                     const int2* __restrict__ seg,
                                     const float* __restrict__ W,
                                     const float* __restrict__ bias,
                                     void* __restrict__ xout, int N) {
    __shared__ float Ws[D][D + 1];
    __shared__ float bs[D];
    int t = threadIdx.x;                       // 256 threads = 4 waves
    for (int i = t; i < D * D; i += 256) Ws[i >> 6][i & 63] = W[i];
    if (t < D) bs[t] = bias[t];
    __syncthreads();

    int wave = t >> 6;
    int lane = t & 63;
    int g = lane >> 4;            // edge sub-stream 0..3
    int c = (lane & 15) << 2;     // feature quad base (elements)
    int nwaves = gridDim.x * 4;
    for (int n = blockIdx.x * 4 + wave; n < N; n += nwaves) {
        int2 sc = seg[n];
        int st = sc.x, cnt = sc.y;
        int ix = 0, iy = 0, iz = 0, iw = 0;
        int k = g;
        for (; k + 4 < cnt; k += 8) {          // unroll x2: both rows in flight
            float2 m0 = perm[st + k];
            float2 m1 = perm[st + k + 4];
            int s0 = __float_as_int(m0.x);
            int s1 = __float_as_int(m1.x);
            uint2 u0 = *reinterpret_cast<const uint2*>(&xb[(size_t)s0 * D + c]);
            uint2 u1 = *reinterpret_cast<const uint2*>(&xb[(size_t)s1 * D + c]);
            float w0 = m0.y, w1 = m1.y;
            ix += (int)(w0 * __uint_as_float(u0.x << 16))
                + (int)(w1 * __uint_as_float(u1.x << 16));
            iy += (int)(w0 * __uint_as_float(u0.x & 0xffff0000u))
                + (int)(w1 * __uint_as_float(u1.x & 0xffff0000u));
            iz += (int)(w0 * __uint_as_float(u0.y << 16))
                + (int)(w1 * __uint_as_float(u1.y << 16));
            iw += (int)(w0 * __uint_as_float(u0.y & 0xffff0000u))
                + (int)(w1 * __uint_as_float(u1.y & 0xffff0000u));
        }
        if (k < cnt) {                          // tail (at most one per group)
            float2 m0 = perm[st + k];
            int s0 = __float_as_int(m0.x);
            uint2 u0 = *reinterpret_cast<const uint2*>(&xb[(size_t)s0 * D + c]);
            float w0 = m0.y;
            ix += (int)(w0 * __uint_as_float(u0.x << 16));
            iy += (int)(w0 * __uint_as_float(u0.x & 0xffff0000u));
            iz += (int)(w0 * __uint_as_float(u0.y << 16));
            iw += (int)(w0 * __uint_as_float(u0.y & 0xffff0000u));
        }
        // integer reduce across the 4 groups (order-free)
        #pragma unroll
        for (int mask = 16; mask <= 32; mask <<= 1) {
            ix += __shfl_xor(ix, mask);
            iy += __shfl_xor(iy, mask);
            iz += __shfl_xor(iz, mask);
            iw += __shfl_xor(iw, mask);
        }
        float ax = (float)ix * FP_INV;
        float ay = (float)iy * FP_INV;
        float az = (float)iz * FP_INV;
        float aw = (float)iw * FP_INV;
        // fused 64x64 linear: 4 independent fma chains (16 deep each)
        float o0 = 0.f, o1 = 0.f, o2 = 0.f, o3 = 0.f;
        #pragma unroll
        for (int q = 0; q < 16; ++q) {
            o0 = fmaf(__int_as_float(__builtin_amdgcn_readlane(__float_as_int(ax), q)), Ws[lane][4 * q + 0], o0);
            o1 = fmaf(__int_as_float(__builtin_amdgcn_readlane(__float_as_int(ay), q)), Ws[lane][4 * q + 1], o1);
            o2 = fmaf(__int_as_float(__builtin_amdgcn_readlane(__float_as_int(az), q)), Ws[lane][4 * q + 2], o2);
            o3 = fmaf(__int_as_float(__builtin_amdgcn_readlane(__float_as_int(aw), q)), Ws[lane][4 * q + 3], o3);
        }
        float o = fmaxf(bs[lane] + ((o0 + o1) + (o2 + o3)), 0.0f);
        if (OUT_BF) ((unsigned short*)xout)[(size_t)n * D + lane] = f2bf(o);
        else        ((float*)xout)[(size_t)n * D + lane] = o;
    }
}

// ---------- fallback (int-atomic path, deterministic, f32) if ws too small ----------
__global__ void rpi_scatter_kernel(const float* __restrict__ x,
                                   const int* __restrict__ src,
                                   const int* __restrict__ dst,
                                   const float* __restrict__ ew,
                                   int* __restrict__ agg, int E) {
    int tid = blockIdx.x * blockDim.x + threadIdx.x;
    int e = tid >> 4;
    if (e >= E) return;
    int c = (tid & 15) << 2;
    int s = src[e], d = dst[e];
    float w = ew[e] * FP_SCALE;
    float4 v = *reinterpret_cast<const float4*>(&x[(size_t)s * D + c]);
    int* o = &agg[(size_t)d * D + c];
    atomicAdd(o + 0, (int)(w * v.x));
    atomicAdd(o + 1, (int)(w * v.y));
    atomicAdd(o + 2, (int)(w * v.z));
    atomicAdd(o + 3, (int)(w * v.w));
}

__global__ void rpi_linear_relu_kernel(const int* __restrict__ agg,
                                       const float* __restrict__ W,
                                       const float* __restrict__ b,
                                       float* __restrict__ out, int N) {
    __shared__ float Ws[D][D + 1];
    __shared__ float bs[D];
    int t = threadIdx.x;
    for (int i = t; i < D * D; i += 256) Ws[i >> 6][i & 63] = W[i];
    if (t < D) bs[t] = b[t];
    __syncthreads();
    int wave = t >> 6, lane = t & 63;
    int nwaves = gridDim.x * 4;
    for (int n = blockIdx.x * 4 + wave; n < N; n += nwaves) {
        const int* arow = &agg[(size_t)n * D];
        float acc = bs[lane];
        #pragma unroll
        for (int d = 0; d < D; ++d) acc = fmaf((float)arow[d] * FP_INV, Ws[lane][d], acc);
        out[(size_t)n * D + lane] = fmaxf(acc, 0.0f);
    }
}

extern "C" void kernel_launch(void* const* d_in, const int* in_sizes, int n_in,
                              void* d_out, int out_size, void* d_ws, size_t ws_size,
                              hipStream_t stream) {
    const float* x0 = (const float*)d_in[0];   // [N, 64]
    const int*   ei = (const int*)d_in[1];     // [2, E]
    const float* ew = (const float*)d_in[2];   // [E]
    const float* W  = (const float*)d_in[3];   // [64, 64]
    const float* b  = (const float*)d_in[4];   // [64]
    float* out = (float*)d_out;                // [N, 64]

    int N = in_sizes[0] / D;
    int E = in_sizes[2];
    const int* src = ei;
    const int* dst = ei + E;

    size_t xeb      = (size_t)N * D * sizeof(unsigned short);  // bf16 x buffer
    size_t intBytes = ((size_t)3 * N + 4) * sizeof(int);       // seg(2N) + cursor(N) + total
    size_t need     = 2 * xeb + intBytes + (size_t)E * sizeof(float2);

    if (ws_size >= need) {
        unsigned short* xb1 = (unsigned short*)d_ws;
        unsigned short* xb2 = xb1 + (size_t)N * D;
        int2*  seg    = (int2*)((char*)d_ws + 2 * xeb);
        int*   cursor = (int*)(seg + N);
        int*   total  = cursor + N;
        float2* perm  = (float2*)((char*)d_ws + 2 * xeb + intBytes);

        hipMemsetAsync(cursor, 0, (size_t)(N + 2) * sizeof(int), stream);  // cursor + total
        int eb = (E + 255) / 256;
        int nb = (N + 255) / 256;
        int n4 = N * D / 4;
        hist_kernel <<<eb, 256, 0, stream>>>(dst, cursor, E);
        alloc_kernel<<<nb, 256, 0, stream>>>(cursor, seg, total, N);
        fill_kernel <<<eb, 256, 0, stream>>>(src, dst, ew, cursor, perm, E);
        cvt_kernel  <<<(n4 + 255) / 256, 256, 0, stream>>>(x0, xb1, n4);

        gather_linear_kernel<true> <<<4096, 256, 0, stream>>>(xb1, perm, seg, W, b, xb2, N);
        gather_linear_kernel<true> <<<4096, 256, 0, stream>>>(xb2, perm, seg, W, b, xb1, N);
        gather_linear_kernel<false><<<4096, 256, 0, stream>>>(xb1, perm, seg, W, b, out, N);
    } else {
        int* agg = (int*)d_ws;
        const float* xcur = x0;
        int sb = (E * 16 + 255) / 256;
        for (int it = 0; it < 3; ++it) {
            hipMemsetAsync(agg, 0, (size_t)N * D * sizeof(int), stream);
            rpi_scatter_kernel<<<sb, 256, 0, stream>>>(xcur, src, dst, ew, agg, E);
            rpi_linear_relu_kernel<<<2048, 256, 0, stream>>>(agg, W, b, out, N);
            xcur = out;
        }
    }
}